// Round 8
// baseline (186.328 us; speedup 1.0000x reference)
//
#include <hip/hip_runtime.h>
#include <stddef.h>

typedef unsigned short u16;
typedef unsigned int u32;
typedef __attribute__((ext_vector_type(4))) float f32x4;
typedef __attribute__((ext_vector_type(8))) u16 u16x8;
typedef __attribute__((ext_vector_type(4))) u16 u16x4;
typedef __attribute__((ext_vector_type(8))) short s16x8;
typedef __attribute__((ext_vector_type(4))) u32 u32x4;

#define MFMA16 __builtin_amdgcn_mfma_f32_16x16x32_bf16

__device__ __forceinline__ u16 f2bf(float f) {
  u32 u = __float_as_uint(f);
  return (u16)((u + 0x7FFFu + ((u >> 16) & 1u)) >> 16);
}
__device__ __forceinline__ u32 cvt_pk_bf16(float lo, float hi) {
  u32 r; asm("v_cvt_pk_bf16_f32 %0, %1, %2" : "=v"(r) : "v"(lo), "v"(hi)); return r;
}

union frag_u { u32x4 u; s16x8 s; };

// B=32, T=500, C=256, H=8, d=32
// ws (<= 32,768,000 B):
//   [0         ..16,384,000) qkbuf [16000][512] bf16 (Q | K)
//   [16,384,000..24,576,000) vt    [32][256][500] bf16 (V^T)
//   [24,576,000..24,969,216) WtA   [768][256] bf16
//   [24,969,216..25,100,288) WtP   [256][256] bf16

// ---------------------------------------------------------------------------
// Transpose both weights in one launch. y<12: W_attn (N=768); else W_proj.
__global__ __launch_bounds__(256) void transpose_both(
    const float* __restrict__ Wa, const float* __restrict__ Wp,
    u16* __restrict__ WtA, u16* __restrict__ WtP)
{
  __shared__ u16 T[64][72];
  const int tid = threadIdx.x;
  const int yy = blockIdx.y;
  const float* W; u16* Wt; int N, n0;
  if (yy < 12) { W = Wa; Wt = WtA; N = 768; n0 = yy * 64; }
  else         { W = Wp; Wt = WtP; N = 256; n0 = (yy - 12) * 64; }
  const int k0 = blockIdx.x * 64;
#pragma unroll
  for (int it = 0; it < 4; ++it) {
    const int r = it * 16 + (tid >> 4);
    const int c = (tid & 15) * 4;
    f32x4 v = *(const f32x4*)&W[(size_t)(k0 + r) * N + n0 + c];
    u16x4 o;
    o[0] = f2bf(v[0]); o[1] = f2bf(v[1]); o[2] = f2bf(v[2]); o[3] = f2bf(v[3]);
    *(u16x4*)&T[r][c] = o;
  }
  __syncthreads();
#pragma unroll
  for (int it = 0; it < 4; ++it) {
    const int n = it * 16 + (tid >> 4);
    const int kc = (tid & 15) * 4;
    u16x4 o;
    o[0] = T[kc + 0][n]; o[1] = T[kc + 1][n];
    o[2] = T[kc + 2][n]; o[3] = T[kc + 3][n];
    *(u16x4*)&Wt[(size_t)(n0 + n) * 256 + k0 + kc] = o;
  }
}

// ---------------------------------------------------------------------------
// Kernel 1: qkv GEMM, A-stationary, 32-row blocks (grid 500), 8 waves.
// Wave w covers cols [w*96, w*96+96). x read exactly once (f32->bf16 in LDS).
__global__ __launch_bounds__(512, 4) void gemm_qkv(
    const float* __restrict__ x, const u16* __restrict__ WtA,
    const float* __restrict__ bias, u16* __restrict__ qkbuf, u16* __restrict__ vt)
{
  __shared__ u16 As[32][264];
  const int tid = threadIdx.x;
  const int lane = tid & 63;
  const int w = tid >> 6;
  const int cl = lane & 15, g = lane >> 4;
  const int m0 = blockIdx.x * 32;

  // stage x panel 32x256 -> bf16 LDS
#pragma unroll
  for (int it = 0; it < 2; ++it) {
    const int ci = tid + it * 512;          // 1024 chunks of 8
    const int row = ci >> 5;
    const int c8 = (ci & 31) * 8;
    f32x4 lo = *(const f32x4*)&x[(size_t)(m0 + row) * 256 + c8];
    f32x4 hi = *(const f32x4*)&x[(size_t)(m0 + row) * 256 + c8 + 4];
    u32x4 p;
    p[0] = cvt_pk_bf16(lo[0], lo[1]); p[1] = cvt_pk_bf16(lo[2], lo[3]);
    p[2] = cvt_pk_bf16(hi[0], hi[1]); p[3] = cvt_pk_bf16(hi[2], hi[3]);
    *(u32x4*)&As[row][c8] = p;
  }
  __syncthreads();

  f32x4 acc[2][6];
#pragma unroll
  for (int mi = 0; mi < 2; ++mi)
#pragma unroll
    for (int nf = 0; nf < 6; ++nf) acc[mi][nf] = (f32x4){0.f, 0.f, 0.f, 0.f};

#pragma unroll
  for (int kt = 0; kt < 8; ++kt) {
    s16x8 af0 = *(const s16x8*)&As[cl][kt * 32 + g * 8];
    s16x8 af1 = *(const s16x8*)&As[16 + cl][kt * 32 + g * 8];
    s16x8 bf[6];
#pragma unroll
    for (int nf = 0; nf < 6; ++nf)
      bf[nf] = *(const s16x8*)&WtA[(size_t)(w * 96 + nf * 16 + cl) * 256 + kt * 32 + g * 8];
#pragma unroll
    for (int nf = 0; nf < 6; ++nf) {
      acc[0][nf] = MFMA16(af0, bf[nf], acc[0][nf], 0, 0, 0);
      acc[1][nf] = MFMA16(af1, bf[nf], acc[1][nf], 0, 0, 0);
    }
  }
#pragma unroll
  for (int nf = 0; nf < 6; ++nf) {
    const int n = w * 96 + nf * 16;
    const float bb = bias[n + cl];
    if (n < 512) {
#pragma unroll
      for (int mi = 0; mi < 2; ++mi)
#pragma unroll
        for (int r = 0; r < 4; ++r) {
          const int m = m0 + mi * 16 + g * 4 + r;
          qkbuf[(size_t)m * 512 + n + cl] = f2bf(acc[mi][nf][r] + bb);
        }
    } else {
      const int cb = n - 512 + cl;
#pragma unroll
      for (int mi = 0; mi < 2; ++mi)
#pragma unroll
        for (int r = 0; r < 4; ++r) {
          const int m = m0 + mi * 16 + g * 4 + r;
          const int b2 = m / 500;
          const int t2 = m - b2 * 500;
          vt[(size_t)(b2 * 256 + cb) * 500 + t2] = f2bf(acc[mi][nf][r] + bb);
        }
    }
  }
}

// ---------------------------------------------------------------------------
// Kernel 2: pred GEMM. Grid 512 (8 xcd * 4 b * 16 tiles of 128x128), but now
// 512 thr = 8 waves (wave = 64x32) for 16 waves/CU, with explicit ping-pong
// register double-buffering of the kt fragments (load kt+1 before MFMA kt).
// pred[b] = sigmoid( sum_kt pw[kt]*scale * (Q_kt @ K_kt^T) ), f32 out (NT).
__global__ __launch_bounds__(512, 4) void pred_gemm(
    const u16* __restrict__ qk, const float* __restrict__ pw_g,
    float* __restrict__ pred)
{
  const int tid = threadIdx.x;
  const int lane = tid & 63;
  const int w = tid >> 6;                // 8 waves: 2 row groups x 4 col groups
  const int cl = lane & 15, g = lane >> 4;
  const int lin = blockIdx.x;            // 512 = 8 xcd * 4 b * 16 tiles
  const int xcd = lin & 7, idx = lin >> 3;
  const int b = xcd * 4 + (idx >> 4);
  const int tile = idx & 15;
  const int tm = tile >> 2, tn = tile & 3;
  const int r0 = tm * 128 + (w >> 2) * 64;   // q-row base (64 rows)
  const int c0 = tn * 128 + (w & 3) * 32;    // s-col base (32 cols)
  const float scale = 0.17677669529663687f;

  const u16* qkb = qk + (size_t)b * 500 * 512;
  float fw[8];
#pragma unroll
  for (int h = 0; h < 8; ++h) fw[h] = pw_g[h] * scale;

  f32x4 acc[4][2];
#pragma unroll
  for (int mi = 0; mi < 4; ++mi)
#pragma unroll
    for (int ni = 0; ni < 2; ++ni) acc[mi][ni] = (f32x4){0.f, 0.f, 0.f, 0.f};

  auto loadk = [&](int kt, s16x8* af, s16x8* bf) {
    const int k0 = kt * 32;
#pragma unroll
    for (int mi = 0; mi < 4; ++mi) {
      int t = r0 + mi * 16 + cl; if (t > 499) t = 499;
      af[mi] = *(const s16x8*)&qkb[(size_t)t * 512 + k0 + g * 8];
    }
#pragma unroll
    for (int ni = 0; ni < 2; ++ni) {
      int s = c0 + ni * 16 + cl; if (s > 499) s = 499;
      bf[ni] = *(const s16x8*)&qkb[(size_t)s * 512 + 256 + k0 + g * 8];
    }
  };
  auto computek = [&](int kt, const s16x8* af, const s16x8* bf) {
    const f32x4 zf = (f32x4){0.f, 0.f, 0.f, 0.f};
    const float f = fw[kt];
#pragma unroll
    for (int mi = 0; mi < 4; ++mi)
#pragma unroll
      for (int ni = 0; ni < 2; ++ni) {
        f32x4 part = MFMA16(af[mi], bf[ni], zf, 0, 0, 0);
#pragma unroll
        for (int r = 0; r < 4; ++r) acc[mi][ni][r] = fmaf(f, part[r], acc[mi][ni][r]);
      }
  };

  s16x8 afA[4], bfA[2], afB[4], bfB[2];
  loadk(0, afA, bfA);
#pragma unroll
  for (int kt = 0; kt < 8; kt += 2) {
    if (kt + 1 < 8) loadk(kt + 1, afB, bfB);
    computek(kt, afA, bfA);
    if (kt + 2 < 8) loadk(kt + 2, afA, bfA);
    if (kt + 1 < 8) computek(kt + 1, afB, bfB);
  }

#pragma unroll
  for (int mi = 0; mi < 4; ++mi)
#pragma unroll
    for (int ni = 0; ni < 2; ++ni) {
      const int s = c0 + ni * 16 + cl;
#pragma unroll
      for (int r = 0; r < 4; ++r) {
        const int t = r0 + mi * 16 + g * 4 + r;
        if (t < 500 && s < 500) {
          const float v = 1.f / (1.f + __expf(-acc[mi][ni][r]));
          __builtin_nontemporal_store(v, &pred[(size_t)(b * 500 + t) * 500 + s]);
        }
      }
    }
}

// ---------------------------------------------------------------------------
// Kernel 3: fused value attention + output projection.
// Block = (b, 32 q-rows), 8 waves; wave = head. Attention is wave-local
// (no LDS/barriers); O staged to LDS once; proj sweeps W_proj^T from L2.
__global__ __launch_bounds__(512, 4) void attn_proj(
    const u16* __restrict__ qk, const u16* __restrict__ vt,
    const u16* __restrict__ WtP, const float* __restrict__ bias,
    float* __restrict__ out)
{
  __shared__ u16 ctxs[32][264];
  const int tid = threadIdx.x;
  const int w = tid >> 6;                // head
  const int lane = tid & 63;
  const int cl = lane & 15, g = lane >> 4;
  const int lin = blockIdx.x;            // 512 = 8 xcd * 4 b * 16 qg
  const int xcd = lin & 7, idx = lin >> 3;
  const int b = xcd * 4 + (idx >> 4);
  const int t0 = (idx & 15) * 32;
  const float scale = 0.17677669529663687f;

  const u16* qkb = qk + (size_t)b * 500 * 512;
  const u16* vtb = vt + (size_t)b * 256 * 500;

  s16x8 qf[2];
#pragma unroll
  for (int qi = 0; qi < 2; ++qi) {
    int tq = t0 + qi * 16 + cl; if (tq > 499) tq = 499;
    qf[qi] = *(const s16x8*)&qkb[(size_t)tq * 512 + w * 32 + g * 8];
  }
  f32x4 of[2][2];
  float lsum[2] = {0.f, 0.f};
#pragma unroll
  for (int qi = 0; qi < 2; ++qi) {
    of[qi][0] = (f32x4){0.f, 0.f, 0.f, 0.f};
    of[qi][1] = (f32x4){0.f, 0.f, 0.f, 0.f};
  }
  const int sA = (g & 1) * 32 + cl;
  const int sB = sA + 16;
  const bool hiHalf = (lane >= 32);

#pragma unroll 1
  for (int st = 0; st < 8; ++st) {
    const int s0 = st * 64;
    s16x8 kf[4];
#pragma unroll
    for (int si = 0; si < 4; ++si) {
      int sr = s0 + si * 16 + cl; if (sr > 499) sr = 499;
      kf[si] = *(const s16x8*)&qkb[(size_t)sr * 512 + 256 + w * 32 + g * 8];
    }
    s16x8 vf[2][2];
#pragma unroll
    for (int di = 0; di < 2; ++di)
#pragma unroll
      for (int s32 = 0; s32 < 2; ++s32)
        vf[di][s32] = *(const s16x8*)&vtb[(size_t)(w * 32 + di * 16 + cl) * 500 +
                                          s0 + s32 * 32 + g * 8];
    const f32x4 zf = (f32x4){0.f, 0.f, 0.f, 0.f};
    u32 P2[2][4][2];
#pragma unroll
    for (int qi = 0; qi < 2; ++qi) {
#pragma unroll
      for (int si = 0; si < 4; ++si) {
        f32x4 St = MFMA16(kf[si], qf[qi], zf, 0, 0, 0);
        float pv[4];
#pragma unroll
        for (int r = 0; r < 4; ++r) {
          int sidx = s0 + si * 16 + g * 4 + r;
          float e = __expf(St[r] * scale);
          pv[r] = (sidx < 500) ? e : 0.f;
          lsum[qi] += pv[r];
        }
        P2[qi][si][0] = cvt_pk_bf16(pv[0], pv[1]);
        P2[qi][si][1] = cvt_pk_bf16(pv[2], pv[3]);
      }
    }
#pragma unroll
    for (int s32 = 0; s32 < 2; ++s32) {
#pragma unroll
      for (int qi = 0; qi < 2; ++qi) {
        u32 Z0 = hiHalf ? P2[qi][2 * s32 + 1][0] : P2[qi][2 * s32][0];
        u32 Z1 = hiHalf ? P2[qi][2 * s32 + 1][1] : P2[qi][2 * s32][1];
        frag_u fu;
        fu.u[0] = (u32)__shfl((int)Z0, sA);
        fu.u[1] = (u32)__shfl((int)Z1, sA);
        fu.u[2] = (u32)__shfl((int)Z0, sB);
        fu.u[3] = (u32)__shfl((int)Z1, sB);
        of[qi][0] = MFMA16(fu.s, vf[0][s32], of[qi][0], 0, 0, 0);
        of[qi][1] = MFMA16(fu.s, vf[1][s32], of[qi][1], 0, 0, 0);
      }
    }
  }
  // O / l -> LDS ctx tile (rows = local q, cols = channel)
#pragma unroll
  for (int qi = 0; qi < 2; ++qi) {
    float l2 = lsum[qi] + __shfl_xor(lsum[qi], 16);
    l2 += __shfl_xor(l2, 32);
#pragma unroll
    for (int r = 0; r < 4; ++r) {
      const float inv = 1.f / __shfl(l2, g * 4 + r);
      const int row = qi * 16 + g * 4 + r;
      ctxs[row][w * 32 + cl]      = f2bf(of[qi][0][r] * inv);
      ctxs[row][w * 32 + 16 + cl] = f2bf(of[qi][1][r] * inv);
    }
  }
  __syncthreads();

  // projection: wave w computes out[t0..t0+31][w*32..w*32+31]
  const int n0 = w * 32;
  f32x4 acc[2][2];
#pragma unroll
  for (int mi = 0; mi < 2; ++mi)
#pragma unroll
    for (int ni = 0; ni < 2; ++ni) acc[mi][ni] = (f32x4){0.f, 0.f, 0.f, 0.f};
#pragma unroll
  for (int kt = 0; kt < 8; ++kt) {
    s16x8 af[2], bf[2];
#pragma unroll
    for (int mi = 0; mi < 2; ++mi)
      af[mi] = *(const s16x8*)&ctxs[mi * 16 + cl][kt * 32 + g * 8];
#pragma unroll
    for (int ni = 0; ni < 2; ++ni)
      bf[ni] = *(const s16x8*)&WtP[(size_t)(n0 + ni * 16 + cl) * 256 + kt * 32 + g * 8];
#pragma unroll
    for (int mi = 0; mi < 2; ++mi)
#pragma unroll
      for (int ni = 0; ni < 2; ++ni)
        acc[mi][ni] = MFMA16(af[mi], bf[ni], acc[mi][ni], 0, 0, 0);
  }
  float bb[2] = { bias[n0 + cl], bias[n0 + 16 + cl] };
#pragma unroll
  for (int mi = 0; mi < 2; ++mi)
#pragma unroll
    for (int ni = 0; ni < 2; ++ni)
#pragma unroll
      for (int r = 0; r < 4; ++r) {
        const int t = t0 + mi * 16 + g * 4 + r;
        if (t < 500) {
          const float v = acc[mi][ni][r] + bb[ni];
          __builtin_nontemporal_store(v, &out[(size_t)(b * 500 + t) * 256 + n0 + ni * 16 + cl]);
        }
      }
}

// ---------------------------------------------------------------------------
extern "C" void kernel_launch(void* const* d_in, const int* in_sizes, int n_in,
                              void* d_out, int out_size, void* d_ws, size_t ws_size,
                              hipStream_t stream)
{
  const float* x      = (const float*)d_in[0];  // [32,500,256]
  const float* W_attn = (const float*)d_in[1];  // [256,768]
  const float* b_attn = (const float*)d_in[2];  // [768]
  const float* p_w    = (const float*)d_in[3];  // [8]
  const float* W_proj = (const float*)d_in[4];  // [256,256]
  const float* b_proj = (const float*)d_in[5];  // [256]

  float* pred   = (float*)d_out;                // [32,500,500]
  float* valout = pred + 8000000;               // [32,500,256]

  u16* qkbuf = (u16*)d_ws;                          // 16,384,000 B
  u16* vt    = (u16*)((char*)d_ws + 16384000);      //  8,192,000 B
  u16* WtA   = (u16*)((char*)d_ws + 24576000);      //    393,216 B
  u16* WtP   = (u16*)((char*)d_ws + 24969216);      //    131,072 B

  hipLaunchKernelGGL(transpose_both, dim3(4, 16), dim3(256), 0, stream,
                     W_attn, W_proj, WtA, WtP);
  hipLaunchKernelGGL(gemm_qkv, dim3(500), dim3(512), 0, stream,
                     x, WtA, b_attn, qkbuf, vt);
  hipLaunchKernelGGL(pred_gemm, dim3(512), dim3(512), 0, stream,
                     qkbuf, p_w, pred);
  hipLaunchKernelGGL(attn_proj, dim3(512), dim3(512), 0, stream,
                     qkbuf, vt, WtP, b_proj, valout);
}

// Round 9
// 118.715 us; speedup vs baseline: 1.5695x; 1.5695x over previous
//
#include <hip/hip_runtime.h>
#include <stddef.h>

typedef unsigned short u16;
typedef unsigned int u32;
typedef unsigned long long u64;
typedef __attribute__((ext_vector_type(4))) float f32x4;
typedef __attribute__((ext_vector_type(8))) u16 u16x8;
typedef __attribute__((ext_vector_type(4))) u16 u16x4;
typedef __attribute__((ext_vector_type(8))) short s16x8;
typedef __attribute__((ext_vector_type(4))) u32 u32x4;

#define MFMA16 __builtin_amdgcn_mfma_f32_16x16x32_bf16

__device__ __forceinline__ u16 f2bf(float f) {
  u32 u = __float_as_uint(f);
  return (u16)((u + 0x7FFFu + ((u >> 16) & 1u)) >> 16);
}
__device__ __forceinline__ u32 cvt_pk_bf16(float lo, float hi) {
  u32 r; asm("v_cvt_pk_bf16_f32 %0, %1, %2" : "=v"(r) : "v"(lo), "v"(hi)); return r;
}

union frag_u { u32x4 u; s16x8 s; };

// B=32, T=500, C=256, H=8, d=32
// ws (<= 32,768,000 B):
//   [0         ..16,384,000) qkbuf [16000][512] bf16 (Q | K)
//   [16,384,000..24,576,000) vt    [32][256][500] bf16 (V^T)
//   [24,576,000..24,969,216) WtA   [768][256] bf16
//   [24,969,216..25,100,288) WtP   [256][256] bf16

// ---------------------------------------------------------------------------
// Transpose both weights in one launch. y<12: W_attn (N=768); else W_proj.
__global__ __launch_bounds__(256) void transpose_both(
    const float* __restrict__ Wa, const float* __restrict__ Wp,
    u16* __restrict__ WtA, u16* __restrict__ WtP)
{
  __shared__ u16 T[64][72];
  const int tid = threadIdx.x;
  const int yy = blockIdx.y;
  const float* W; u16* Wt; int N, n0;
  if (yy < 12) { W = Wa; Wt = WtA; N = 768; n0 = yy * 64; }
  else         { W = Wp; Wt = WtP; N = 256; n0 = (yy - 12) * 64; }
  const int k0 = blockIdx.x * 64;
#pragma unroll
  for (int it = 0; it < 4; ++it) {
    const int r = it * 16 + (tid >> 4);
    const int c = (tid & 15) * 4;
    f32x4 v = *(const f32x4*)&W[(size_t)(k0 + r) * N + n0 + c];
    u16x4 o;
    o[0] = f2bf(v[0]); o[1] = f2bf(v[1]); o[2] = f2bf(v[2]); o[3] = f2bf(v[3]);
    *(u16x4*)&T[r][c] = o;
  }
  __syncthreads();
#pragma unroll
  for (int it = 0; it < 4; ++it) {
    const int n = it * 16 + (tid >> 4);
    const int kc = (tid & 15) * 4;
    u16x4 o;
    o[0] = T[kc + 0][n]; o[1] = T[kc + 1][n];
    o[2] = T[kc + 2][n]; o[3] = T[kc + 3][n];
    *(u16x4*)&Wt[(size_t)(n0 + n) * 256 + k0 + kc] = o;
  }
}

// ---------------------------------------------------------------------------
// Kernel 1: qkv GEMM, A-stationary, 32-row blocks (grid 500), 8 waves.
__global__ __launch_bounds__(512, 4) void gemm_qkv(
    const float* __restrict__ x, const u16* __restrict__ WtA,
    const float* __restrict__ bias, u16* __restrict__ qkbuf, u16* __restrict__ vt)
{
  __shared__ u16 As[32][264];
  const int tid = threadIdx.x;
  const int lane = tid & 63;
  const int w = tid >> 6;
  const int cl = lane & 15, g = lane >> 4;
  const int m0 = blockIdx.x * 32;

#pragma unroll
  for (int it = 0; it < 2; ++it) {
    const int ci = tid + it * 512;
    const int row = ci >> 5;
    const int c8 = (ci & 31) * 8;
    f32x4 lo = *(const f32x4*)&x[(size_t)(m0 + row) * 256 + c8];
    f32x4 hi = *(const f32x4*)&x[(size_t)(m0 + row) * 256 + c8 + 4];
    u32x4 p;
    p[0] = cvt_pk_bf16(lo[0], lo[1]); p[1] = cvt_pk_bf16(lo[2], lo[3]);
    p[2] = cvt_pk_bf16(hi[0], hi[1]); p[3] = cvt_pk_bf16(hi[2], hi[3]);
    *(u32x4*)&As[row][c8] = p;
  }
  __syncthreads();

  f32x4 acc[2][6];
#pragma unroll
  for (int mi = 0; mi < 2; ++mi)
#pragma unroll
    for (int nf = 0; nf < 6; ++nf) acc[mi][nf] = (f32x4){0.f, 0.f, 0.f, 0.f};

#pragma unroll
  for (int kt = 0; kt < 8; ++kt) {
    s16x8 af0 = *(const s16x8*)&As[cl][kt * 32 + g * 8];
    s16x8 af1 = *(const s16x8*)&As[16 + cl][kt * 32 + g * 8];
    s16x8 bf[6];
#pragma unroll
    for (int nf = 0; nf < 6; ++nf)
      bf[nf] = *(const s16x8*)&WtA[(size_t)(w * 96 + nf * 16 + cl) * 256 + kt * 32 + g * 8];
#pragma unroll
    for (int nf = 0; nf < 6; ++nf) {
      acc[0][nf] = MFMA16(af0, bf[nf], acc[0][nf], 0, 0, 0);
      acc[1][nf] = MFMA16(af1, bf[nf], acc[1][nf], 0, 0, 0);
    }
  }
#pragma unroll
  for (int nf = 0; nf < 6; ++nf) {
    const int n = w * 96 + nf * 16;
    const float bb = bias[n + cl];
    if (n < 512) {
#pragma unroll
      for (int mi = 0; mi < 2; ++mi)
#pragma unroll
        for (int r = 0; r < 4; ++r) {
          const int m = m0 + mi * 16 + g * 4 + r;
          qkbuf[(size_t)m * 512 + n + cl] = f2bf(acc[mi][nf][r] + bb);
        }
    } else {
      const int cb = n - 512 + cl;
#pragma unroll
      for (int mi = 0; mi < 2; ++mi)
#pragma unroll
        for (int r = 0; r < 4; ++r) {
          const int m = m0 + mi * 16 + g * 4 + r;
          const int b2 = m / 500;
          const int t2 = m - b2 * 500;
          vt[(size_t)(b2 * 256 + cb) * 500 + t2] = f2bf(acc[mi][nf][r] + bb);
        }
    }
  }
}

// ---------------------------------------------------------------------------
// Kernel 2: pred GEMM (round-7 geometry) + LDS epilogue for full-line stores.
// Grid 512 = 8 xcd * 4 b * 16 tiles of 128x128; 4 waves; wave = 64x64.
__global__ __launch_bounds__(256) void pred_gemm(
    const u16* __restrict__ qk, const float* __restrict__ pw_g,
    float* __restrict__ pred)
{
  __shared__ float eps[4][32 * 66];      // per-wave staging, 33.8 KB
  const int tid = threadIdx.x;
  const int lane = tid & 63;
  const int w = tid >> 6;
  const int cl = lane & 15, g = lane >> 4;
  const int lin = blockIdx.x;
  const int xcd = lin & 7, idx = lin >> 3;
  const int b = xcd * 4 + (idx >> 4);
  const int tile = idx & 15;
  const int tm = tile >> 2, tn = tile & 3;
  const int r0 = tm * 128 + (w >> 1) * 64;
  const int c0 = tn * 128 + (w & 1) * 64;
  const float scale = 0.17677669529663687f;

  const u16* qkb = qk + (size_t)b * 500 * 512;
  float fw[8];
#pragma unroll
  for (int h = 0; h < 8; ++h) fw[h] = pw_g[h] * scale;

  f32x4 acc[4][4];
#pragma unroll
  for (int mi = 0; mi < 4; ++mi)
#pragma unroll
    for (int ni = 0; ni < 4; ++ni) acc[mi][ni] = (f32x4){0.f, 0.f, 0.f, 0.f};

#pragma unroll 2
  for (int kt = 0; kt < 8; ++kt) {
    const int k0 = kt * 32;
    s16x8 af[4], bf[4];
#pragma unroll
    for (int mi = 0; mi < 4; ++mi) {
      int t = r0 + mi * 16 + cl; if (t > 499) t = 499;
      af[mi] = *(const s16x8*)&qkb[(size_t)t * 512 + k0 + g * 8];
    }
#pragma unroll
    for (int ni = 0; ni < 4; ++ni) {
      int s = c0 + ni * 16 + cl; if (s > 499) s = 499;
      bf[ni] = *(const s16x8*)&qkb[(size_t)s * 512 + 256 + k0 + g * 8];
    }
    const f32x4 zf = (f32x4){0.f, 0.f, 0.f, 0.f};
    const float f = fw[kt];
#pragma unroll
    for (int mi = 0; mi < 4; ++mi)
#pragma unroll
      for (int ni = 0; ni < 4; ++ni) {
        f32x4 part = MFMA16(af[mi], bf[ni], zf, 0, 0, 0);
#pragma unroll
        for (int r = 0; r < 4; ++r) acc[mi][ni][r] = fmaf(f, part[r], acc[mi][ni][r]);
      }
  }

  // Epilogue: two 32-row halves through per-wave LDS; full-line NT stores.
#pragma unroll
  for (int half = 0; half < 2; ++half) {
    // stage sigmoid(acc) -> eps (banks spread: g shifts 4 rows = +264 f32 = +8 banks)
#pragma unroll
    for (int mi2 = 0; mi2 < 2; ++mi2) {
#pragma unroll
      for (int ni = 0; ni < 4; ++ni)
#pragma unroll
        for (int r = 0; r < 4; ++r) {
          const int row = mi2 * 16 + g * 4 + r;
          const float v = 1.f / (1.f + __expf(-acc[half * 2 + mi2][ni][r]));
          eps[w][row * 66 + ni * 16 + cl] = v;
        }
    }
    // read back 2 rows/instr (lane>>5), 2 cols/lane -> 2x 256B contiguous NT
#pragma unroll
    for (int it = 0; it < 16; ++it) {
      const int lrow = it * 2 + (lane >> 5);
      const int t = r0 + half * 32 + lrow;
      const int c = c0 + (lane & 31) * 2;
      const u64 val = *(const u64*)&eps[w][lrow * 66 + (lane & 31) * 2];
      if (t < 500 && c < 500)
        __builtin_nontemporal_store(val, (u64*)&pred[(size_t)(b * 500 + t) * 500 + c]);
    }
  }
}

// ---------------------------------------------------------------------------
// Kernel 3: fused value attention + output projection, LDS store epilogue.
__global__ __launch_bounds__(512, 4) void attn_proj(
    const u16* __restrict__ qk, const u16* __restrict__ vt,
    const u16* __restrict__ WtP, const float* __restrict__ bias,
    float* __restrict__ out)
{
  __shared__ u16 ctxs[32][264];
  __shared__ float outs[32][264];        // f32 epilogue staging, 33.8 KB
  const int tid = threadIdx.x;
  const int w = tid >> 6;                // head
  const int lane = tid & 63;
  const int cl = lane & 15, g = lane >> 4;
  const int lin = blockIdx.x;
  const int xcd = lin & 7, idx = lin >> 3;
  const int b = xcd * 4 + (idx >> 4);
  const int t0 = (idx & 15) * 32;
  const float scale = 0.17677669529663687f;

  const u16* qkb = qk + (size_t)b * 500 * 512;
  const u16* vtb = vt + (size_t)b * 256 * 500;

  s16x8 qf[2];
#pragma unroll
  for (int qi = 0; qi < 2; ++qi) {
    int tq = t0 + qi * 16 + cl; if (tq > 499) tq = 499;
    qf[qi] = *(const s16x8*)&qkb[(size_t)tq * 512 + w * 32 + g * 8];
  }
  f32x4 of[2][2];
  float lsum[2] = {0.f, 0.f};
#pragma unroll
  for (int qi = 0; qi < 2; ++qi) {
    of[qi][0] = (f32x4){0.f, 0.f, 0.f, 0.f};
    of[qi][1] = (f32x4){0.f, 0.f, 0.f, 0.f};
  }
  const int sA = (g & 1) * 32 + cl;
  const int sB = sA + 16;
  const bool hiHalf = (lane >= 32);

#pragma unroll 1
  for (int st = 0; st < 8; ++st) {
    const int s0 = st * 64;
    s16x8 kf[4];
#pragma unroll
    for (int si = 0; si < 4; ++si) {
      int sr = s0 + si * 16 + cl; if (sr > 499) sr = 499;
      kf[si] = *(const s16x8*)&qkb[(size_t)sr * 512 + 256 + w * 32 + g * 8];
    }
    s16x8 vf[2][2];
#pragma unroll
    for (int di = 0; di < 2; ++di)
#pragma unroll
      for (int s32 = 0; s32 < 2; ++s32)
        vf[di][s32] = *(const s16x8*)&vtb[(size_t)(w * 32 + di * 16 + cl) * 500 +
                                          s0 + s32 * 32 + g * 8];
    const f32x4 zf = (f32x4){0.f, 0.f, 0.f, 0.f};
    u32 P2[2][4][2];
#pragma unroll
    for (int qi = 0; qi < 2; ++qi) {
#pragma unroll
      for (int si = 0; si < 4; ++si) {
        f32x4 St = MFMA16(kf[si], qf[qi], zf, 0, 0, 0);
        float pv[4];
#pragma unroll
        for (int r = 0; r < 4; ++r) {
          int sidx = s0 + si * 16 + g * 4 + r;
          float e = __expf(St[r] * scale);
          pv[r] = (sidx < 500) ? e : 0.f;
          lsum[qi] += pv[r];
        }
        P2[qi][si][0] = cvt_pk_bf16(pv[0], pv[1]);
        P2[qi][si][1] = cvt_pk_bf16(pv[2], pv[3]);
      }
    }
#pragma unroll
    for (int s32 = 0; s32 < 2; ++s32) {
#pragma unroll
      for (int qi = 0; qi < 2; ++qi) {
        u32 Z0 = hiHalf ? P2[qi][2 * s32 + 1][0] : P2[qi][2 * s32][0];
        u32 Z1 = hiHalf ? P2[qi][2 * s32 + 1][1] : P2[qi][2 * s32][1];
        frag_u fu;
        fu.u[0] = (u32)__shfl((int)Z0, sA);
        fu.u[1] = (u32)__shfl((int)Z1, sA);
        fu.u[2] = (u32)__shfl((int)Z0, sB);
        fu.u[3] = (u32)__shfl((int)Z1, sB);
        of[qi][0] = MFMA16(fu.s, vf[0][s32], of[qi][0], 0, 0, 0);
        of[qi][1] = MFMA16(fu.s, vf[1][s32], of[qi][1], 0, 0, 0);
      }
    }
  }
  // O / l -> LDS ctx tile (bf16)
#pragma unroll
  for (int qi = 0; qi < 2; ++qi) {
    float l2 = lsum[qi] + __shfl_xor(lsum[qi], 16);
    l2 += __shfl_xor(l2, 32);
#pragma unroll
    for (int r = 0; r < 4; ++r) {
      const float inv = 1.f / __shfl(l2, g * 4 + r);
      const int row = qi * 16 + g * 4 + r;
      ctxs[row][w * 32 + cl]      = f2bf(of[qi][0][r] * inv);
      ctxs[row][w * 32 + 16 + cl] = f2bf(of[qi][1][r] * inv);
    }
  }
  __syncthreads();

  // projection: wave w computes out[t0..t0+31][w*32..w*32+31] -> outs (f32)
  const int n0 = w * 32;
  f32x4 acc[2][2];
#pragma unroll
  for (int mi = 0; mi < 2; ++mi)
#pragma unroll
    for (int ni = 0; ni < 2; ++ni) acc[mi][ni] = (f32x4){0.f, 0.f, 0.f, 0.f};
#pragma unroll
  for (int kt = 0; kt < 8; ++kt) {
    s16x8 af[2], bf[2];
#pragma unroll
    for (int mi = 0; mi < 2; ++mi)
      af[mi] = *(const s16x8*)&ctxs[mi * 16 + cl][kt * 32 + g * 8];
#pragma unroll
    for (int ni = 0; ni < 2; ++ni)
      bf[ni] = *(const s16x8*)&WtP[(size_t)(n0 + ni * 16 + cl) * 256 + kt * 32 + g * 8];
#pragma unroll
    for (int mi = 0; mi < 2; ++mi)
#pragma unroll
      for (int ni = 0; ni < 2; ++ni)
        acc[mi][ni] = MFMA16(af[mi], bf[ni], acc[mi][ni], 0, 0, 0);
  }
  float bb[2] = { bias[n0 + cl], bias[n0 + 16 + cl] };
#pragma unroll
  for (int mi = 0; mi < 2; ++mi)
#pragma unroll
    for (int ni = 0; ni < 2; ++ni)
#pragma unroll
      for (int r = 0; r < 4; ++r) {
        const int row = mi * 16 + g * 4 + r;
        outs[row][n0 + ni * 16 + cl] = acc[mi][ni][r] + bb[ni];
      }
  __syncthreads();

  // cooperative full-line NT stores: 512 thr x 16 f32 = 32x256 tile
  {
    const int orow = tid >> 4;          // 0..31
    const int ocp = (tid & 15) * 16;    // 16 f32 per thread
    const int t = t0 + orow;
    if (t < 500) {
      float* gp = &out[(size_t)(b * 500 + t) * 256 + ocp];
#pragma unroll
      for (int j = 0; j < 4; ++j) {
        f32x4 v = *(const f32x4*)&outs[orow][ocp + j * 4];
        __builtin_nontemporal_store(v, (f32x4*)&gp[j * 4]);
      }
    }
  }
}

// ---------------------------------------------------------------------------
extern "C" void kernel_launch(void* const* d_in, const int* in_sizes, int n_in,
                              void* d_out, int out_size, void* d_ws, size_t ws_size,
                              hipStream_t stream)
{
  const float* x      = (const float*)d_in[0];  // [32,500,256]
  const float* W_attn = (const float*)d_in[1];  // [256,768]
  const float* b_attn = (const float*)d_in[2];  // [768]
  const float* p_w    = (const float*)d_in[3];  // [8]
  const float* W_proj = (const float*)d_in[4];  // [256,256]
  const float* b_proj = (const float*)d_in[5];  // [256]

  float* pred   = (float*)d_out;                // [32,500,500]
  float* valout = pred + 8000000;               // [32,500,256]

  u16* qkbuf = (u16*)d_ws;                          // 16,384,000 B
  u16* vt    = (u16*)((char*)d_ws + 16384000);      //  8,192,000 B
  u16* WtA   = (u16*)((char*)d_ws + 24576000);      //    393,216 B
  u16* WtP   = (u16*)((char*)d_ws + 24969216);      //    131,072 B

  hipLaunchKernelGGL(transpose_both, dim3(4, 16), dim3(256), 0, stream,
                     W_attn, W_proj, WtA, WtP);
  hipLaunchKernelGGL(gemm_qkv, dim3(500), dim3(512), 0, stream,
                     x, WtA, b_attn, qkbuf, vt);
  hipLaunchKernelGGL(pred_gemm, dim3(512), dim3(256), 0, stream,
                     qkbuf, p_w, pred);
  hipLaunchKernelGGL(attn_proj, dim3(512), dim3(512), 0, stream,
                     qkbuf, vt, WtP, b_proj, valout);
}

// Round 10
// 109.721 us; speedup vs baseline: 1.6982x; 1.0820x over previous
//
#include <hip/hip_runtime.h>
#include <stddef.h>

typedef unsigned short u16;
typedef unsigned int u32;
typedef unsigned long long u64;
typedef __attribute__((ext_vector_type(4))) float f32x4;
typedef __attribute__((ext_vector_type(8))) u16 u16x8;
typedef __attribute__((ext_vector_type(4))) u16 u16x4;
typedef __attribute__((ext_vector_type(8))) short s16x8;
typedef __attribute__((ext_vector_type(4))) u32 u32x4;

#define MFMA16 __builtin_amdgcn_mfma_f32_16x16x32_bf16

__device__ __forceinline__ u16 f2bf(float f) {
  u32 u = __float_as_uint(f);
  return (u16)((u + 0x7FFFu + ((u >> 16) & 1u)) >> 16);
}
__device__ __forceinline__ u32 cvt_pk_bf16(float lo, float hi) {
  u32 r; asm("v_cvt_pk_bf16_f32 %0, %1, %2" : "=v"(r) : "v"(lo), "v"(hi)); return r;
}

union frag_u { u32x4 u; s16x8 s; };

// B=32, T=500, C=256, H=8, d=32
// ws (<= 32,768,000 B):
//   [0         ..16,384,000) qkbuf [16000][512] bf16 (Q | K)
//   [16,384,000..24,576,000) vt    [32][256][500] bf16 (V^T)
//   [24,576,000..24,969,216) WtA   [768][256] bf16
//   [24,969,216..25,100,288) WtP   [256][256] bf16

// ---------------------------------------------------------------------------
// Transpose both weights in one launch. y<12: W_attn (N=768); else W_proj.
__global__ __launch_bounds__(256) void transpose_both(
    const float* __restrict__ Wa, const float* __restrict__ Wp,
    u16* __restrict__ WtA, u16* __restrict__ WtP)
{
  __shared__ u16 T[64][72];
  const int tid = threadIdx.x;
  const int yy = blockIdx.y;
  const float* W; u16* Wt; int N, n0;
  if (yy < 12) { W = Wa; Wt = WtA; N = 768; n0 = yy * 64; }
  else         { W = Wp; Wt = WtP; N = 256; n0 = (yy - 12) * 64; }
  const int k0 = blockIdx.x * 64;
#pragma unroll
  for (int it = 0; it < 4; ++it) {
    const int r = it * 16 + (tid >> 4);
    const int c = (tid & 15) * 4;
    f32x4 v = *(const f32x4*)&W[(size_t)(k0 + r) * N + n0 + c];
    u16x4 o;
    o[0] = f2bf(v[0]); o[1] = f2bf(v[1]); o[2] = f2bf(v[2]); o[3] = f2bf(v[3]);
    *(u16x4*)&T[r][c] = o;
  }
  __syncthreads();
#pragma unroll
  for (int it = 0; it < 4; ++it) {
    const int n = it * 16 + (tid >> 4);
    const int kc = (tid & 15) * 4;
    u16x4 o;
    o[0] = T[kc + 0][n]; o[1] = T[kc + 1][n];
    o[2] = T[kc + 2][n]; o[3] = T[kc + 3][n];
    *(u16x4*)&Wt[(size_t)(n0 + n) * 256 + k0 + kc] = o;
  }
}

// ---------------------------------------------------------------------------
// Kernel 1: qkv GEMM, A-stationary, 32-row blocks (grid 500), 8 waves.
__global__ __launch_bounds__(512, 4) void gemm_qkv(
    const float* __restrict__ x, const u16* __restrict__ WtA,
    const float* __restrict__ bias, u16* __restrict__ qkbuf, u16* __restrict__ vt)
{
  __shared__ u16 As[32][264];
  const int tid = threadIdx.x;
  const int lane = tid & 63;
  const int w = tid >> 6;
  const int cl = lane & 15, g = lane >> 4;
  const int m0 = blockIdx.x * 32;

#pragma unroll
  for (int it = 0; it < 2; ++it) {
    const int ci = tid + it * 512;
    const int row = ci >> 5;
    const int c8 = (ci & 31) * 8;
    f32x4 lo = *(const f32x4*)&x[(size_t)(m0 + row) * 256 + c8];
    f32x4 hi = *(const f32x4*)&x[(size_t)(m0 + row) * 256 + c8 + 4];
    u32x4 p;
    p[0] = cvt_pk_bf16(lo[0], lo[1]); p[1] = cvt_pk_bf16(lo[2], lo[3]);
    p[2] = cvt_pk_bf16(hi[0], hi[1]); p[3] = cvt_pk_bf16(hi[2], hi[3]);
    *(u32x4*)&As[row][c8] = p;
  }
  __syncthreads();

  f32x4 acc[2][6];
#pragma unroll
  for (int mi = 0; mi < 2; ++mi)
#pragma unroll
    for (int nf = 0; nf < 6; ++nf) acc[mi][nf] = (f32x4){0.f, 0.f, 0.f, 0.f};

#pragma unroll
  for (int kt = 0; kt < 8; ++kt) {
    s16x8 af0 = *(const s16x8*)&As[cl][kt * 32 + g * 8];
    s16x8 af1 = *(const s16x8*)&As[16 + cl][kt * 32 + g * 8];
    s16x8 bf[6];
#pragma unroll
    for (int nf = 0; nf < 6; ++nf)
      bf[nf] = *(const s16x8*)&WtA[(size_t)(w * 96 + nf * 16 + cl) * 256 + kt * 32 + g * 8];
#pragma unroll
    for (int nf = 0; nf < 6; ++nf) {
      acc[0][nf] = MFMA16(af0, bf[nf], acc[0][nf], 0, 0, 0);
      acc[1][nf] = MFMA16(af1, bf[nf], acc[1][nf], 0, 0, 0);
    }
  }
#pragma unroll
  for (int nf = 0; nf < 6; ++nf) {
    const int n = w * 96 + nf * 16;
    const float bb = bias[n + cl];
    if (n < 512) {
#pragma unroll
      for (int mi = 0; mi < 2; ++mi)
#pragma unroll
        for (int r = 0; r < 4; ++r) {
          const int m = m0 + mi * 16 + g * 4 + r;
          qkbuf[(size_t)m * 512 + n + cl] = f2bf(acc[mi][nf][r] + bb);
        }
    } else {
      const int cb = n - 512 + cl;
#pragma unroll
      for (int mi = 0; mi < 2; ++mi)
#pragma unroll
        for (int r = 0; r < 4; ++r) {
          const int m = m0 + mi * 16 + g * 4 + r;
          const int b2 = m / 500;
          const int t2 = m - b2 * 500;
          vt[(size_t)(b2 * 256 + cb) * 500 + t2] = f2bf(acc[mi][nf][r] + bb);
        }
    }
  }
}

// ---------------------------------------------------------------------------
// Kernel 2: pred GEMM (round-7 geometry) + LDS epilogue for full-line stores.
__global__ __launch_bounds__(256) void pred_gemm(
    const u16* __restrict__ qk, const float* __restrict__ pw_g,
    float* __restrict__ pred)
{
  __shared__ float eps[4][32 * 66];
  const int tid = threadIdx.x;
  const int lane = tid & 63;
  const int w = tid >> 6;
  const int cl = lane & 15, g = lane >> 4;
  const int lin = blockIdx.x;
  const int xcd = lin & 7, idx = lin >> 3;
  const int b = xcd * 4 + (idx >> 4);
  const int tile = idx & 15;
  const int tm = tile >> 2, tn = tile & 3;
  const int r0 = tm * 128 + (w >> 1) * 64;
  const int c0 = tn * 128 + (w & 1) * 64;
  const float scale = 0.17677669529663687f;

  const u16* qkb = qk + (size_t)b * 500 * 512;
  float fw[8];
#pragma unroll
  for (int h = 0; h < 8; ++h) fw[h] = pw_g[h] * scale;

  f32x4 acc[4][4];
#pragma unroll
  for (int mi = 0; mi < 4; ++mi)
#pragma unroll
    for (int ni = 0; ni < 4; ++ni) acc[mi][ni] = (f32x4){0.f, 0.f, 0.f, 0.f};

#pragma unroll 2
  for (int kt = 0; kt < 8; ++kt) {
    const int k0 = kt * 32;
    s16x8 af[4], bf[4];
#pragma unroll
    for (int mi = 0; mi < 4; ++mi) {
      int t = r0 + mi * 16 + cl; if (t > 499) t = 499;
      af[mi] = *(const s16x8*)&qkb[(size_t)t * 512 + k0 + g * 8];
    }
#pragma unroll
    for (int ni = 0; ni < 4; ++ni) {
      int s = c0 + ni * 16 + cl; if (s > 499) s = 499;
      bf[ni] = *(const s16x8*)&qkb[(size_t)s * 512 + 256 + k0 + g * 8];
    }
    const f32x4 zf = (f32x4){0.f, 0.f, 0.f, 0.f};
    const float f = fw[kt];
#pragma unroll
    for (int mi = 0; mi < 4; ++mi)
#pragma unroll
      for (int ni = 0; ni < 4; ++ni) {
        f32x4 part = MFMA16(af[mi], bf[ni], zf, 0, 0, 0);
#pragma unroll
        for (int r = 0; r < 4; ++r) acc[mi][ni][r] = fmaf(f, part[r], acc[mi][ni][r]);
      }
  }

#pragma unroll
  for (int half = 0; half < 2; ++half) {
#pragma unroll
    for (int mi2 = 0; mi2 < 2; ++mi2) {
#pragma unroll
      for (int ni = 0; ni < 4; ++ni)
#pragma unroll
        for (int r = 0; r < 4; ++r) {
          const int row = mi2 * 16 + g * 4 + r;
          const float v = 1.f / (1.f + __expf(-acc[half * 2 + mi2][ni][r]));
          eps[w][row * 66 + ni * 16 + cl] = v;
        }
    }
#pragma unroll
    for (int it = 0; it < 16; ++it) {
      const int lrow = it * 2 + (lane >> 5);
      const int t = r0 + half * 32 + lrow;
      const int c = c0 + (lane & 31) * 2;
      const u64 val = *(const u64*)&eps[w][lrow * 66 + (lane & 31) * 2];
      if (t < 500 && c < 500)
        __builtin_nontemporal_store(val, (u64*)&pred[(size_t)(b * 500 + t) * 500 + c]);
    }
  }
}

// ---------------------------------------------------------------------------
// Kernel 3: fused value attention + output projection.
// Ping-pong K prefetch + early V issue; wave-contiguous NT store epilogue.
__global__ __launch_bounds__(512, 4) void attn_proj(
    const u16* __restrict__ qk, const u16* __restrict__ vt,
    const u16* __restrict__ WtP, const float* __restrict__ bias,
    float* __restrict__ out)
{
  __shared__ u16 ctxs[32][264];
  __shared__ float outs[32][264];
  const int tid = threadIdx.x;
  const int w = tid >> 6;                // head
  const int lane = tid & 63;
  const int cl = lane & 15, g = lane >> 4;
  const int lin = blockIdx.x;
  const int xcd = lin & 7, idx = lin >> 3;
  const int b = xcd * 4 + (idx >> 4);
  const int t0 = (idx & 15) * 32;
  const float scale = 0.17677669529663687f;

  const u16* qkb = qk + (size_t)b * 500 * 512;
  const u16* vtb = vt + (size_t)b * 256 * 500;

  s16x8 qf[2];
#pragma unroll
  for (int qi = 0; qi < 2; ++qi) {
    int tq = t0 + qi * 16 + cl; if (tq > 499) tq = 499;
    qf[qi] = *(const s16x8*)&qkb[(size_t)tq * 512 + w * 32 + g * 8];
  }
  f32x4 of[2][2];
  float lsum[2] = {0.f, 0.f};
#pragma unroll
  for (int qi = 0; qi < 2; ++qi) {
    of[qi][0] = (f32x4){0.f, 0.f, 0.f, 0.f};
    of[qi][1] = (f32x4){0.f, 0.f, 0.f, 0.f};
  }
  const int sA = (g & 1) * 32 + cl;
  const int sB = sA + 16;
  const bool hiHalf = (lane >= 32);

  auto loadK = [&](int st, s16x8* kf) {
    const int s0 = st * 64;
#pragma unroll
    for (int si = 0; si < 4; ++si) {
      int sr = s0 + si * 16 + cl; if (sr > 499) sr = 499;
      kf[si] = *(const s16x8*)&qkb[(size_t)sr * 512 + 256 + w * 32 + g * 8];
    }
  };
  auto loadV = [&](int st, s16x8 (*vf)[2]) {
    const int s0 = st * 64;
#pragma unroll
    for (int di = 0; di < 2; ++di)
#pragma unroll
      for (int s32 = 0; s32 < 2; ++s32)
        vf[di][s32] = *(const s16x8*)&vtb[(size_t)(w * 32 + di * 16 + cl) * 500 +
                                          s0 + s32 * 32 + g * 8];
  };
  auto compute = [&](int st, const s16x8* kf, const s16x8 (*vf)[2]) {
    const int s0 = st * 64;
    const f32x4 zf = (f32x4){0.f, 0.f, 0.f, 0.f};
    u32 P2[2][4][2];
#pragma unroll
    for (int qi = 0; qi < 2; ++qi) {
#pragma unroll
      for (int si = 0; si < 4; ++si) {
        f32x4 St = MFMA16(kf[si], qf[qi], zf, 0, 0, 0);
        float pv[4];
#pragma unroll
        for (int r = 0; r < 4; ++r) {
          int sidx = s0 + si * 16 + g * 4 + r;
          float e = __expf(St[r] * scale);
          pv[r] = (sidx < 500) ? e : 0.f;
          lsum[qi] += pv[r];
        }
        P2[qi][si][0] = cvt_pk_bf16(pv[0], pv[1]);
        P2[qi][si][1] = cvt_pk_bf16(pv[2], pv[3]);
      }
    }
#pragma unroll
    for (int s32 = 0; s32 < 2; ++s32) {
#pragma unroll
      for (int qi = 0; qi < 2; ++qi) {
        u32 Z0 = hiHalf ? P2[qi][2 * s32 + 1][0] : P2[qi][2 * s32][0];
        u32 Z1 = hiHalf ? P2[qi][2 * s32 + 1][1] : P2[qi][2 * s32][1];
        frag_u fu;
        fu.u[0] = (u32)__shfl((int)Z0, sA);
        fu.u[1] = (u32)__shfl((int)Z1, sA);
        fu.u[2] = (u32)__shfl((int)Z0, sB);
        fu.u[3] = (u32)__shfl((int)Z1, sB);
        of[qi][0] = MFMA16(fu.s, vf[0][s32], of[qi][0], 0, 0, 0);
        of[qi][1] = MFMA16(fu.s, vf[1][s32], of[qi][1], 0, 0, 0);
      }
    }
  };

  s16x8 kA[4], kB[4], vf[2][2];
  loadK(0, kA);
#pragma unroll
  for (int st = 0; st < 8; st += 2) {
    loadV(st, vf);
    loadK(st + 1, kB);
    compute(st, kA, vf);
    loadV(st + 1, vf);
    if (st + 2 < 8) loadK(st + 2, kA);
    compute(st + 1, kB, vf);
  }

  // O / l -> LDS ctx tile (bf16)
#pragma unroll
  for (int qi = 0; qi < 2; ++qi) {
    float l2 = lsum[qi] + __shfl_xor(lsum[qi], 16);
    l2 += __shfl_xor(l2, 32);
#pragma unroll
    for (int r = 0; r < 4; ++r) {
      const float inv = 1.f / __shfl(l2, g * 4 + r);
      const int row = qi * 16 + g * 4 + r;
      ctxs[row][w * 32 + cl]      = f2bf(of[qi][0][r] * inv);
      ctxs[row][w * 32 + 16 + cl] = f2bf(of[qi][1][r] * inv);
    }
  }
  __syncthreads();

  // projection: wave w computes out[t0..t0+31][w*32..w*32+31] -> outs (f32)
  const int n0 = w * 32;
  f32x4 acc[2][2];
#pragma unroll
  for (int mi = 0; mi < 2; ++mi)
#pragma unroll
    for (int ni = 0; ni < 2; ++ni) acc[mi][ni] = (f32x4){0.f, 0.f, 0.f, 0.f};
#pragma unroll
  for (int kt = 0; kt < 8; ++kt) {
    s16x8 af[2], bf[2];
#pragma unroll
    for (int mi = 0; mi < 2; ++mi)
      af[mi] = *(const s16x8*)&ctxs[mi * 16 + cl][kt * 32 + g * 8];
#pragma unroll
    for (int ni = 0; ni < 2; ++ni)
      bf[ni] = *(const s16x8*)&WtP[(size_t)(n0 + ni * 16 + cl) * 256 + kt * 32 + g * 8];
#pragma unroll
    for (int mi = 0; mi < 2; ++mi)
#pragma unroll
      for (int ni = 0; ni < 2; ++ni)
        acc[mi][ni] = MFMA16(af[mi], bf[ni], acc[mi][ni], 0, 0, 0);
  }
  float bb[2] = { bias[n0 + cl], bias[n0 + 16 + cl] };
#pragma unroll
  for (int mi = 0; mi < 2; ++mi)
#pragma unroll
    for (int ni = 0; ni < 2; ++ni)
#pragma unroll
      for (int r = 0; r < 4; ++r) {
        const int row = mi * 16 + g * 4 + r;
        outs[row][n0 + ni * 16 + cl] = acc[mi][ni][r] + bb[ni];
      }
  __syncthreads();

  // store epilogue: wave w stores rows {w, w+8, w+16, w+24}; per instruction
  // 64 lanes x 16B = 1024B contiguous (one full valout row).
#pragma unroll
  for (int it = 0; it < 4; ++it) {
    const int row = it * 8 + w;
    const int t = t0 + row;
    if (t < 500) {
      f32x4 v = *(const f32x4*)&outs[row][lane * 4];
      __builtin_nontemporal_store(v, (f32x4*)&out[(size_t)(b * 500 + t) * 256 + lane * 4]);
    }
  }
}

// ---------------------------------------------------------------------------
extern "C" void kernel_launch(void* const* d_in, const int* in_sizes, int n_in,
                              void* d_out, int out_size, void* d_ws, size_t ws_size,
                              hipStream_t stream)
{
  const float* x      = (const float*)d_in[0];  // [32,500,256]
  const float* W_attn = (const float*)d_in[1];  // [256,768]
  const float* b_attn = (const float*)d_in[2];  // [768]
  const float* p_w    = (const float*)d_in[3];  // [8]
  const float* W_proj = (const float*)d_in[4];  // [256,256]
  const float* b_proj = (const float*)d_in[5];  // [256]

  float* pred   = (float*)d_out;                // [32,500,500]
  float* valout = pred + 8000000;               // [32,500,256]

  u16* qkbuf = (u16*)d_ws;                          // 16,384,000 B
  u16* vt    = (u16*)((char*)d_ws + 16384000);      //  8,192,000 B
  u16* WtA   = (u16*)((char*)d_ws + 24576000);      //    393,216 B
  u16* WtP   = (u16*)((char*)d_ws + 24969216);      //    131,072 B

  hipLaunchKernelGGL(transpose_both, dim3(4, 16), dim3(256), 0, stream,
                     W_attn, W_proj, WtA, WtP);
  hipLaunchKernelGGL(gemm_qkv, dim3(500), dim3(512), 0, stream,
                     x, WtA, b_attn, qkbuf, vt);
  hipLaunchKernelGGL(pred_gemm, dim3(512), dim3(256), 0, stream,
                     qkbuf, p_w, pred);
  hipLaunchKernelGGL(attn_proj, dim3(512), dim3(512), 0, stream,
                     qkbuf, vt, WtP, b_proj, valout);
}